// Round 5
// baseline (1276.449 us; speedup 1.0000x reference)
//
#include <hip/hip_runtime.h>

// CeNN layer, bf16 MFMA implicit GEMM, v5: NHWC state + software-pipelined
// staging (batch loads -> convert) + epilogue src/icp preload before barrier.
// Iter: dst = 0.9*src + 0.1*conv3x3(nonlin(src), A_w) + ICp

typedef short  bf16x8 __attribute__((ext_vector_type(8)));
typedef float  f32x4  __attribute__((ext_vector_type(4)));

#define HH 128
#define WW 128
#define NCH 64
#define GROWS 8
#define NSLOT 10               // rows y0-1 .. y0+8
#define XS 32                  // output strip width
#define NC 34                  // staged cols x0-1 .. x0+32
#define ROWB 128               // 64 cin * 2B
#define SLOTB (NC * ROWB)      // 4352
#define ACTB (NSLOT * SLOTB)   // 43520
#define WSETB 73728            // one frag-ordered bf16 weight set

__device__ __align__(16) unsigned char g_fw[3 * WSETB];

__device__ __forceinline__ float nonlin(float x) {
    const float A = 0.01f;
    float y = fminf(x, fmaf(A, x, 1.0f - A));
    return fmaxf(y, fmaf(A, y, -(1.0f - A)));
}
__device__ __forceinline__ unsigned int f2bf(float f) {
    unsigned int u = __float_as_uint(f);
    u += 0x7fffu + ((u >> 16) & 1u);       // RNE
    return u >> 16;
}

// w[cout][cin][3x3] -> fragment order. chunk=(cb*18+kb)*64+ln ;
// value j: k = kb*32+(ln>>4)*8+j ; k = tap*64+cin.
__global__ __launch_bounds__(256)
void prep_w(const float* __restrict__ rw, const float* __restrict__ bw,
            const float* __restrict__ aw) {
    const float* w = blockIdx.x == 0 ? rw : (blockIdx.x == 1 ? bw : aw);
    unsigned char* o = g_fw + blockIdx.x * WSETB;
    int chunk = blockIdx.y * 256 + threadIdx.x;        // 0..4607
    int cb  = chunk / 1152;
    int rem = chunk - cb * 1152;
    int kb  = rem >> 6;
    int ln  = rem & 63;
    int cout = cb * 16 + (ln & 15);
    int g    = ln >> 4;
    unsigned int h[8];
    #pragma unroll
    for (int j = 0; j < 8; ++j) {
        int k = kb * 32 + g * 8 + j;
        int tap = k >> 6;
        int cin = k & 63;
        h[j] = f2bf(w[(cout * 64 + cin) * 9 + tap]);
    }
    uint4 v;
    v.x = h[0] | (h[1] << 16);
    v.y = h[2] | (h[3] << 16);
    v.z = h[4] | (h[5] << 16);
    v.w = h[6] | (h[7] << 16);
    *(uint4*)(o + chunk * 16) = v;
}

__device__ __forceinline__ void conv_tile(const char* actl, const unsigned char* fw,
                                          int lane, int wv, f32x4 (&acc)[4][4]) {
    const int l15 = lane & 15;
    const int g4  = lane >> 4;
    #pragma unroll
    for (int kb = 0; kb < 18; ++kb) {
        const int tap  = kb >> 1;
        const int dy   = tap / 3;
        const int dx   = tap - dy * 3;
        const int cinB = (kb & 1) * 64 + g4 * 16;
        bf16x8 af[4];
        #pragma unroll
        for (int cb = 0; cb < 4; ++cb)
            af[cb] = *(const bf16x8*)(fw + ((cb * 18 + kb) * 64 + lane) * 16);
        bf16x8 bfr[4];
        #pragma unroll
        for (int i = 0; i < 4; ++i) {
            int row = wv * 2 + (i >> 1) + dy;
            int c   = (i & 1) * 16 + l15 + dx;
            bfr[i] = *(const bf16x8*)(actl + row * SLOTB + c * ROWB
                                      + (cinB ^ ((c & 7) << 4)));
        }
        #pragma unroll
        for (int cb = 0; cb < 4; ++cb)
            #pragma unroll
            for (int i = 0; i < 4; ++i)
                acc[cb][i] = __builtin_amdgcn_mfma_f32_16x16x32_bf16(
                    af[cb], bfr[i], acc[cb][i], 0, 0, 0);
    }
}

// MODE 0: init: src=x (NCHW). dst=state0 (NHWC)=conv(x,rw)+rb ;
//         dst2=ICp (NHWC)=0.1*(conv(x,bw)+bb+zz+ab)
// MODE 1: iter (NHWC->NHWC): dst = 0.1*conv(nonlin(src),aw)+0.9*src+icp
// MODE 2: final iter: MODE 1 + nonlin, dst written NCHW.
template<int MODE>
__global__ __launch_bounds__(256, 3)
void cenn(const float* __restrict__ src,
          const float* __restrict__ rb, const float* __restrict__ bb,
          const float* __restrict__ zz, const float* __restrict__ ab,
          const float* __restrict__ icp,
          float* __restrict__ dst, float* __restrict__ dst2)
{
    __shared__ __align__(16) char actl[ACTB];
    const int tid  = threadIdx.x;
    const int lane = tid & 63;
    const int wv   = tid >> 6;
    const int l15  = lane & 15;
    const int g4   = lane >> 4;

    // XCD-aware bijective swizzle: 1024 blocks, 128 per XCD chunk (2 images).
    int lin = (blockIdx.z * 16 + blockIdx.y) * 4 + blockIdx.x;
    lin = (lin & 7) * 128 + (lin >> 3);
    const int x0 = (lin & 3) * XS;
    const int y0 = ((lin >> 2) & 15) * GROWS;
    const int n  = lin >> 6;

    f32x4 sld[16], pld[16];

    if constexpr (MODE == 0) {
        // ---- NCHW staging, two-phase: batch 88 scalar loads, then pack ----
        constexpr int NE0 = NSLOT * NC * 8;          // 2720
        constexpr int NI0 = (NE0 + 255) / 256;       // 11
        float l0[NI0][8];
        #pragma unroll
        for (int it = 0; it < NI0; ++it) {
            int idx = it * 256 + tid;
            int r   = idx / (NC * 8);
            int rem = idx - r * (NC * 8);
            int cb8 = rem / NC;
            int c   = rem - cb8 * NC;
            int yc  = min(max(y0 + r - 1, 0), HH - 1);
            int xc  = min(max(x0 + c - 1, 0), WW - 1);
            const float* p = src + ((size_t)(n * NCH + cb8 * 8) * HH + yc) * WW + xc;
            #pragma unroll
            for (int j = 0; j < 8; ++j) l0[it][j] = p[(size_t)j * HH * WW];
        }
        #pragma unroll
        for (int it = 0; it < NI0; ++it) {
            int idx = it * 256 + tid;
            if (idx < NE0) {
                int r   = idx / (NC * 8);
                int rem = idx - r * (NC * 8);
                int cb8 = rem / NC;
                int c   = rem - cb8 * NC;
                int y   = y0 + r - 1;
                int x   = x0 + c - 1;
                bool ok = (unsigned)y < (unsigned)HH && (unsigned)x < (unsigned)WW;
                uint4 v = {0u, 0u, 0u, 0u};
                if (ok) {
                    unsigned int h[8];
                    #pragma unroll
                    for (int j = 0; j < 8; ++j) h[j] = f2bf(l0[it][j]);
                    v.x = h[0] | (h[1] << 16);
                    v.y = h[2] | (h[3] << 16);
                    v.z = h[4] | (h[5] << 16);
                    v.w = h[6] | (h[7] << 16);
                }
                *(uint4*)(actl + r * SLOTB + c * ROWB + ((cb8 * 16) ^ ((c & 7) << 4))) = v;
            }
        }
    } else {
        // ---- NHWC staging, two-phase: batch 22 f32x4 loads, then pack ----
        constexpr int NEL = NSLOT * NC * 16;         // 5440
        constexpr int NIT = (NEL + 255) / 256;       // 22
        f32x4 ld[NIT];
        #pragma unroll
        for (int it = 0; it < NIT; ++it) {
            int idx = it * 256 + tid;
            int r   = idx / (NC * 16);
            int rem = idx - r * (NC * 16);
            int c   = rem >> 4;
            int q   = rem & 15;
            int yc  = min(max(y0 + r - 1, 0), HH - 1);
            int xc  = min(max(x0 + c - 1, 0), WW - 1);
            ld[it]  = *(const f32x4*)(src + ((((size_t)n * HH + yc) * WW + xc) << 6) + q * 4);
        }
        // epilogue preloads: latency hides under staging drain + conv
        #pragma unroll
        for (int cb = 0; cb < 4; ++cb)
            #pragma unroll
            for (int i = 0; i < 4; ++i) {
                int y  = y0 + wv * 2 + (i >> 1);
                int x  = x0 + (i & 1) * 16 + l15;
                int c0 = cb * 16 + g4 * 4;
                size_t base = ((((size_t)n * HH + y) * WW + x) << 6) + c0;
                sld[cb * 4 + i] = *(const f32x4*)(src + base);
                pld[cb * 4 + i] = *(const f32x4*)(icp + base);
            }
        #pragma unroll
        for (int it = 0; it < NIT; ++it) {
            int idx = it * 256 + tid;
            if (idx < NEL) {
                int r   = idx / (NC * 16);
                int rem = idx - r * (NC * 16);
                int c   = rem >> 4;
                int q   = rem & 15;
                int y   = y0 + r - 1;
                int x   = x0 + c - 1;
                bool ok = (unsigned)y < (unsigned)HH && (unsigned)x < (unsigned)WW;
                f32x4 v = ld[it];
                uint2 w2;
                w2.x = f2bf(nonlin(v[0])) | (f2bf(nonlin(v[1])) << 16);
                w2.y = f2bf(nonlin(v[2])) | (f2bf(nonlin(v[3])) << 16);
                if (!ok) { w2.x = 0u; w2.y = 0u; }
                *(uint2*)(actl + r * SLOTB + c * ROWB + ((q * 8) ^ ((c & 7) << 4))) = w2;
            }
        }
    }
    __syncthreads();

    f32x4 acc[4][4];
    #pragma unroll
    for (int a = 0; a < 4; ++a)
        #pragma unroll
        for (int b = 0; b < 4; ++b)
            acc[a][b] = (f32x4){0.f, 0.f, 0.f, 0.f};

    conv_tile(actl, g_fw + (MODE == 0 ? 0 : 2 * WSETB), lane, wv, acc);

    // D map per acc[cb][i]: pixel = l15, couts cb*16+g4*4 + r (contiguous)
    if constexpr (MODE == 0) {
        #pragma unroll
        for (int cb = 0; cb < 4; ++cb)
            #pragma unroll
            for (int i = 0; i < 4; ++i) {
                int y  = y0 + wv * 2 + (i >> 1);
                int x  = x0 + (i & 1) * 16 + l15;
                int c0 = cb * 16 + g4 * 4;
                size_t base = ((((size_t)n * HH + y) * WW + x) << 6) + c0;
                f32x4 o;
                #pragma unroll
                for (int r = 0; r < 4; ++r) o[r] = acc[cb][i][r] + rb[c0 + r];
                *(f32x4*)(dst + base) = o;
            }
        #pragma unroll
        for (int a = 0; a < 4; ++a)
            #pragma unroll
            for (int b = 0; b < 4; ++b)
                acc[a][b] = (f32x4){0.f, 0.f, 0.f, 0.f};
        conv_tile(actl, g_fw + WSETB, lane, wv, acc);
        #pragma unroll
        for (int cb = 0; cb < 4; ++cb)
            #pragma unroll
            for (int i = 0; i < 4; ++i) {
                int y  = y0 + wv * 2 + (i >> 1);
                int x  = x0 + (i & 1) * 16 + l15;
                int c0 = cb * 16 + g4 * 4;
                size_t base = ((((size_t)n * HH + y) * WW + x) << 6) + c0;
                f32x4 o;
                #pragma unroll
                for (int r = 0; r < 4; ++r)
                    o[r] = 0.1f * (acc[cb][i][r] + bb[c0 + r] + zz[c0 + r] + ab[c0 + r]);
                *(f32x4*)(dst2 + base) = o;
            }
    } else {
        #pragma unroll
        for (int cb = 0; cb < 4; ++cb)
            #pragma unroll
            for (int i = 0; i < 4; ++i) {
                int y  = y0 + wv * 2 + (i >> 1);
                int x  = x0 + (i & 1) * 16 + l15;
                int c0 = cb * 16 + g4 * 4;
                f32x4 s = sld[cb * 4 + i];
                f32x4 p = pld[cb * 4 + i];
                if constexpr (MODE == 1) {
                    size_t base = ((((size_t)n * HH + y) * WW + x) << 6) + c0;
                    f32x4 o;
                    #pragma unroll
                    for (int r = 0; r < 4; ++r)
                        o[r] = 0.1f * acc[cb][i][r] + 0.9f * s[r] + p[r];
                    *(f32x4*)(dst + base) = o;
                } else {
                    #pragma unroll
                    for (int r = 0; r < 4; ++r) {
                        float v = 0.1f * acc[cb][i][r] + 0.9f * s[r] + p[r];
                        v = nonlin(v);
                        dst[((size_t)(n * NCH + c0 + r) * HH + y) * WW + x] = v;
                    }
                }
            }
    }
}

extern "C" void kernel_launch(void* const* d_in, const int* in_sizes, int n_in,
                              void* d_out, int out_size, void* d_ws, size_t ws_size,
                              hipStream_t stream) {
    const float* x  = (const float*)d_in[0];
    const float* rw = (const float*)d_in[1];
    const float* rb = (const float*)d_in[2];
    const float* aw = (const float*)d_in[3];
    const float* ab = (const float*)d_in[4];
    const float* bw = (const float*)d_in[5];
    const float* bb = (const float*)d_in[6];
    const float* z  = (const float*)d_in[7];
    float* out = (float*)d_out;

    const size_t plane = (size_t)16 * NCH * HH * WW;   // 16.78M floats
    float* icp = (float*)d_ws;          // ICp plane, NHWC f32
    float* s1  = icp + plane;           // state ping buffer, NHWC f32

    dim3 blk(256, 1, 1), grd(4, 16, 16);   // 1024 blocks

    prep_w<<<dim3(3, 18, 1), blk, 0, stream>>>(rw, bw, aw);
    // state0 (NHWC) -> d_out(raw), ICp (NHWC) -> ws
    cenn<0><<<grd, blk, 0, stream>>>(x, rb, bb, z, ab, nullptr, out, icp);

    // parity: even i reads out, writes s1; odd i reads s1, writes out.
    // i=9 reads s1, writes NCHW final to out.
    for (int i = 0; i < 10; ++i) {
        const float* s = (i & 1) ? s1 : out;
        float*       d = (i & 1) ? out : s1;
        if (i == 9)
            cenn<2><<<grd, blk, 0, stream>>>(s, nullptr, nullptr, nullptr, nullptr, icp, out, nullptr);
        else
            cenn<1><<<grd, blk, 0, stream>>>(s, nullptr, nullptr, nullptr, nullptr, icp, d, nullptr);
    }
}

// Round 6
// 714.570 us; speedup vs baseline: 1.7863x; 1.7863x over previous
//
#include <hip/hip_runtime.h>

// CeNN layer, bf16 MFMA implicit GEMM, v6 = v4 + register-budgeted two-phase
// staging for the iteration kernels (22 batched f32x4 loads, then convert).
// No epilogue preloads (v5's spill). Iter: dst = 0.9*src + 0.1*conv3x3(nonlin(src),A_w) + ICp

typedef short  bf16x8 __attribute__((ext_vector_type(8)));
typedef float  f32x4  __attribute__((ext_vector_type(4)));

#define HH 128
#define WW 128
#define NCH 64
#define GROWS 8
#define NSLOT 10               // rows y0-1 .. y0+8
#define XS 32                  // output strip width
#define NC 34                  // staged cols x0-1 .. x0+32
#define ROWB 128               // 64 cin * 2B
#define SLOTB (NC * ROWB)      // 4352
#define ACTB (NSLOT * SLOTB)   // 43520
#define WSETB 73728            // one frag-ordered bf16 weight set

__device__ __align__(16) unsigned char g_fw[3 * WSETB];

__device__ __forceinline__ float nonlin(float x) {
    const float A = 0.01f;
    float y = fminf(x, fmaf(A, x, 1.0f - A));
    return fmaxf(y, fmaf(A, y, -(1.0f - A)));
}
__device__ __forceinline__ unsigned int f2bf(float f) {
    unsigned int u = __float_as_uint(f);
    u += 0x7fffu + ((u >> 16) & 1u);       // RNE
    return u >> 16;
}

// w[cout][cin][3x3] -> fragment order. chunk=(cb*18+kb)*64+ln ;
// value j: k = kb*32+(ln>>4)*8+j ; k = tap*64+cin.
__global__ __launch_bounds__(256)
void prep_w(const float* __restrict__ rw, const float* __restrict__ bw,
            const float* __restrict__ aw) {
    const float* w = blockIdx.x == 0 ? rw : (blockIdx.x == 1 ? bw : aw);
    unsigned char* o = g_fw + blockIdx.x * WSETB;
    int chunk = blockIdx.y * 256 + threadIdx.x;        // 0..4607
    int cb  = chunk / 1152;
    int rem = chunk - cb * 1152;
    int kb  = rem >> 6;
    int ln  = rem & 63;
    int cout = cb * 16 + (ln & 15);
    int g    = ln >> 4;
    unsigned int h[8];
    #pragma unroll
    for (int j = 0; j < 8; ++j) {
        int k = kb * 32 + g * 8 + j;
        int tap = k >> 6;
        int cin = k & 63;
        h[j] = f2bf(w[(cout * 64 + cin) * 9 + tap]);
    }
    uint4 v;
    v.x = h[0] | (h[1] << 16);
    v.y = h[2] | (h[3] << 16);
    v.z = h[4] | (h[5] << 16);
    v.w = h[6] | (h[7] << 16);
    *(uint4*)(o + chunk * 16) = v;
}

__device__ __forceinline__ void conv_tile(const char* actl, const unsigned char* fw,
                                          int lane, int wv, f32x4 (&acc)[4][4]) {
    const int l15 = lane & 15;
    const int g4  = lane >> 4;
    #pragma unroll
    for (int kb = 0; kb < 18; ++kb) {
        const int tap  = kb >> 1;
        const int dy   = tap / 3;
        const int dx   = tap - dy * 3;
        const int cinB = (kb & 1) * 64 + g4 * 16;
        bf16x8 af[4];
        #pragma unroll
        for (int cb = 0; cb < 4; ++cb)
            af[cb] = *(const bf16x8*)(fw + ((cb * 18 + kb) * 64 + lane) * 16);
        bf16x8 bfr[4];
        #pragma unroll
        for (int i = 0; i < 4; ++i) {
            int row = wv * 2 + (i >> 1) + dy;
            int c   = (i & 1) * 16 + l15 + dx;
            bfr[i] = *(const bf16x8*)(actl + row * SLOTB + c * ROWB
                                      + (cinB ^ ((c & 7) << 4)));
        }
        #pragma unroll
        for (int cb = 0; cb < 4; ++cb)
            #pragma unroll
            for (int i = 0; i < 4; ++i)
                acc[cb][i] = __builtin_amdgcn_mfma_f32_16x16x32_bf16(
                    af[cb], bfr[i], acc[cb][i], 0, 0, 0);
    }
}

// MODE 0: init: src=x (NCHW). dst=state0 (NHWC)=conv(x,rw)+rb ;
//         dst2=ICp (NHWC)=0.1*(conv(x,bw)+bb+zz+ab)
// MODE 1: iter (NHWC->NHWC): dst = 0.1*conv(nonlin(src),aw)+0.9*src+icp
// MODE 2: final iter: MODE 1 + nonlin, dst written NCHW.
template<int MODE>
__global__ __launch_bounds__(256, 3)
void cenn(const float* __restrict__ src,
          const float* __restrict__ rb, const float* __restrict__ bb,
          const float* __restrict__ zz, const float* __restrict__ ab,
          const float* __restrict__ icp,
          float* __restrict__ dst, float* __restrict__ dst2)
{
    __shared__ __align__(16) char actl[ACTB];
    const int tid  = threadIdx.x;
    const int lane = tid & 63;
    const int wv   = tid >> 6;
    const int l15  = lane & 15;
    const int g4   = lane >> 4;

    // XCD-aware bijective swizzle: 1024 blocks, 128 per XCD chunk (2 images).
    int lin = (blockIdx.z * 16 + blockIdx.y) * 4 + blockIdx.x;
    lin = (lin & 7) * 128 + (lin >> 3);
    const int x0 = (lin & 3) * XS;
    const int y0 = ((lin >> 2) & 15) * GROWS;
    const int n  = lin >> 6;

    if constexpr (MODE == 0) {
        // ---- NCHW staging (one dispatch only): load->pack->write loop ----
        for (int idx = tid; idx < NSLOT * NC * 8; idx += 256) {
            int r   = idx / (NC * 8);
            int rem = idx - r * (NC * 8);
            int cb8 = rem / NC;
            int c   = rem - cb8 * NC;
            int y   = y0 + r - 1;
            int x   = x0 + c - 1;
            uint4 v = {0u, 0u, 0u, 0u};
            if ((unsigned)y < (unsigned)HH && (unsigned)x < (unsigned)WW) {
                const float* p = src + ((size_t)(n * NCH + cb8 * 8) * HH + y) * WW + x;
                unsigned int h[8];
                #pragma unroll
                for (int j = 0; j < 8; ++j)
                    h[j] = f2bf(p[(size_t)j * HH * WW]);
                v.x = h[0] | (h[1] << 16);
                v.y = h[2] | (h[3] << 16);
                v.z = h[4] | (h[5] << 16);
                v.w = h[6] | (h[7] << 16);
            }
            *(uint4*)(actl + r * SLOTB + c * ROWB + ((cb8 * 16) ^ ((c & 7) << 4))) = v;
        }
    } else {
        // ---- NHWC staging, two-phase: 22 batched f32x4 loads, then convert ----
        constexpr int NEL = NSLOT * NC * 16;         // 5440
        constexpr int NIT = (NEL + 255) / 256;       // 22
        f32x4 ld[NIT];
        #pragma unroll
        for (int it = 0; it < NIT; ++it) {
            int idx = it * 256 + tid;
            int r   = idx / (NC * 16);
            int rem = idx - r * (NC * 16);
            int c   = rem >> 4;
            int q   = rem & 15;
            int yc  = min(max(y0 + r - 1, 0), HH - 1);
            int xc  = min(max(x0 + c - 1, 0), WW - 1);
            ld[it]  = *(const f32x4*)(src + ((((size_t)n * HH + yc) * WW + xc) << 6) + q * 4);
        }
        #pragma unroll
        for (int it = 0; it < NIT; ++it) {
            int idx = it * 256 + tid;
            if (idx < NEL) {
                int r   = idx / (NC * 16);
                int rem = idx - r * (NC * 16);
                int c   = rem >> 4;
                int q   = rem & 15;
                int y   = y0 + r - 1;
                int x   = x0 + c - 1;
                bool ok = (unsigned)y < (unsigned)HH && (unsigned)x < (unsigned)WW;
                f32x4 v = ld[it];
                uint2 w2;
                w2.x = f2bf(nonlin(v[0])) | (f2bf(nonlin(v[1])) << 16);
                w2.y = f2bf(nonlin(v[2])) | (f2bf(nonlin(v[3])) << 16);
                if (!ok) { w2.x = 0u; w2.y = 0u; }
                *(uint2*)(actl + r * SLOTB + c * ROWB + ((q * 8) ^ ((c & 7) << 4))) = w2;
            }
        }
    }
    __syncthreads();

    f32x4 acc[4][4];
    #pragma unroll
    for (int a = 0; a < 4; ++a)
        #pragma unroll
        for (int b = 0; b < 4; ++b)
            acc[a][b] = (f32x4){0.f, 0.f, 0.f, 0.f};

    conv_tile(actl, g_fw + (MODE == 0 ? 0 : 2 * WSETB), lane, wv, acc);

    // D map per acc[cb][i]: pixel = l15, couts cb*16+g4*4 + r (contiguous)
    if constexpr (MODE == 0) {
        #pragma unroll
        for (int cb = 0; cb < 4; ++cb)
            #pragma unroll
            for (int i = 0; i < 4; ++i) {
                int y  = y0 + wv * 2 + (i >> 1);
                int x  = x0 + (i & 1) * 16 + l15;
                int c0 = cb * 16 + g4 * 4;
                size_t base = ((((size_t)n * HH + y) * WW + x) << 6) + c0;
                f32x4 o;
                #pragma unroll
                for (int r = 0; r < 4; ++r) o[r] = acc[cb][i][r] + rb[c0 + r];
                *(f32x4*)(dst + base) = o;
            }
        #pragma unroll
        for (int a = 0; a < 4; ++a)
            #pragma unroll
            for (int b = 0; b < 4; ++b)
                acc[a][b] = (f32x4){0.f, 0.f, 0.f, 0.f};
        conv_tile(actl, g_fw + WSETB, lane, wv, acc);
        #pragma unroll
        for (int cb = 0; cb < 4; ++cb)
            #pragma unroll
            for (int i = 0; i < 4; ++i) {
                int y  = y0 + wv * 2 + (i >> 1);
                int x  = x0 + (i & 1) * 16 + l15;
                int c0 = cb * 16 + g4 * 4;
                size_t base = ((((size_t)n * HH + y) * WW + x) << 6) + c0;
                f32x4 o;
                #pragma unroll
                for (int r = 0; r < 4; ++r)
                    o[r] = 0.1f * (acc[cb][i][r] + bb[c0 + r] + zz[c0 + r] + ab[c0 + r]);
                *(f32x4*)(dst2 + base) = o;
            }
    } else {
        #pragma unroll
        for (int cb = 0; cb < 4; ++cb)
            #pragma unroll
            for (int i = 0; i < 4; ++i) {
                int y  = y0 + wv * 2 + (i >> 1);
                int x  = x0 + (i & 1) * 16 + l15;
                int c0 = cb * 16 + g4 * 4;
                size_t base = ((((size_t)n * HH + y) * WW + x) << 6) + c0;
                f32x4 s = *(const f32x4*)(src + base);
                f32x4 p = *(const f32x4*)(icp + base);
                if constexpr (MODE == 1) {
                    f32x4 o;
                    #pragma unroll
                    for (int r = 0; r < 4; ++r)
                        o[r] = 0.1f * acc[cb][i][r] + 0.9f * s[r] + p[r];
                    *(f32x4*)(dst + base) = o;
                } else {
                    #pragma unroll
                    for (int r = 0; r < 4; ++r) {
                        float v = 0.1f * acc[cb][i][r] + 0.9f * s[r] + p[r];
                        v = nonlin(v);
                        dst[((size_t)(n * NCH + c0 + r) * HH + y) * WW + x] = v;
                    }
                }
            }
    }
}

extern "C" void kernel_launch(void* const* d_in, const int* in_sizes, int n_in,
                              void* d_out, int out_size, void* d_ws, size_t ws_size,
                              hipStream_t stream) {
    const float* x  = (const float*)d_in[0];
    const float* rw = (const float*)d_in[1];
    const float* rb = (const float*)d_in[2];
    const float* aw = (const float*)d_in[3];
    const float* ab = (const float*)d_in[4];
    const float* bw = (const float*)d_in[5];
    const float* bb = (const float*)d_in[6];
    const float* z  = (const float*)d_in[7];
    float* out = (float*)d_out;

    const size_t plane = (size_t)16 * NCH * HH * WW;   // 16.78M floats
    float* icp = (float*)d_ws;          // ICp plane, NHWC f32
    float* s1  = icp + plane;           // state ping buffer, NHWC f32

    dim3 blk(256, 1, 1), grd(4, 16, 16);   // 1024 blocks

    prep_w<<<dim3(3, 18, 1), blk, 0, stream>>>(rw, bw, aw);
    // state0 (NHWC) -> d_out(raw), ICp (NHWC) -> ws
    cenn<0><<<grd, blk, 0, stream>>>(x, rb, bb, z, ab, nullptr, out, icp);

    // parity: even i reads out, writes s1; odd i reads s1, writes out.
    // i=9 reads s1, writes NCHW final to out.
    for (int i = 0; i < 10; ++i) {
        const float* s = (i & 1) ? s1 : out;
        float*       d = (i & 1) ? out : s1;
        if (i == 9)
            cenn<2><<<grd, blk, 0, stream>>>(s, nullptr, nullptr, nullptr, nullptr, icp, out, nullptr);
        else
            cenn<1><<<grd, blk, 0, stream>>>(s, nullptr, nullptr, nullptr, nullptr, icp, d, nullptr);
    }
}